// Round 7
// baseline (837.305 us; speedup 1.0000x reference)
//
#include <hip/hip_runtime.h>

// ---------------------------------------------------------------------------
// VirusHostCoexistenceModel — 6-node graph:
//   memset -> k0 (Wa/hist/sums/kbuf) -> k_prep (pack+dot/tp/ndt/scan)
//   -> k_sg (gemm+scatter) -> k_gatbn -> k_fin
#define NV   6000
#define NH   6000
#define EV   200000
#define EH   200000
#define EC   32768
#define GCAP 256

typedef __attribute__((ext_vector_type(8))) short bf16x8;
typedef __attribute__((ext_vector_type(4))) float f32x4;

__device__ __forceinline__ unsigned short f2bf(float f){
  unsigned u = __float_as_uint(f);
  u += 0x7FFFu + ((u >> 16) & 1u);        // RNE bf16
  return (unsigned short)(u >> 16);
}
__device__ __forceinline__ float bf2f(unsigned short h){
  return __uint_as_float((unsigned)h << 16);
}

// ===========================================================================
// Dispatch 1 (k0): W·a scalars + edge histogram + edge-weight sums + Kbuf
// blocks: [0,2048) WasWad | [2048,3867) hist | [3867,4123) sums | 4123 kbuf
__global__ __launch_bounds__(256) void k0(
    const float* __restrict__ vW, const float* __restrict__ v_as, const float* __restrict__ v_ad,
    const float* __restrict__ hW, const float* __restrict__ h_as, const float* __restrict__ h_ad,
    const float* __restrict__ vhW, const float* __restrict__ vh_as, const float* __restrict__ vh_ad,
    const float* __restrict__ hvW, const float* __restrict__ hv_as, const float* __restrict__ hv_ad,
    const float* __restrict__ vew, const float* __restrict__ hew,
    const float* __restrict__ v_line, const float* __restrict__ v_atte,
    const float* __restrict__ h_line, const float* __restrict__ h_atte,
    const int* __restrict__ vdst, const int* __restrict__ hdst,
    const int* __restrict__ c1dst, const int* __restrict__ c2dst,
    float* WasV, float* WadV, float* WasH, float* WadH,
    float* WasC1, float* WadC1, float* WasC2, float* WadC2,
    float* sums, float* Kbuf,
    int* cntV, int* cntH, int* cntC1, int* cntC2)
{
  __shared__ float red4[4][2];
  int b = blockIdx.x, t = threadIdx.x;
  int lane = t & 63, w = t >> 6;

  if (b < 2048){                                    // ---- Was/Wad (2 rows/block)
    int m = b >> 9;
    int krow = (b & 511) * 2 + (t >> 7);
    int c = t & 127;
    const float *W, *as_, *ad_; float *Was, *Wad;
    switch (m){
      case 0:  W=vW;  as_=v_as;  ad_=v_ad;  Was=WasV;  Wad=WadV;  break;
      case 1:  W=hW;  as_=h_as;  ad_=h_ad;  Was=WasH;  Wad=WadH;  break;
      case 2:  W=vhW; as_=vh_as; ad_=vh_ad; Was=WasC1; Wad=WadC1; break;
      default: W=hvW; as_=hv_as; ad_=hv_ad; Was=WasC2; Wad=WadC2; break;
    }
    const float* Wr = W + (size_t)krow * 384;
    for (int h = 0; h < 3; h++){
      float x = Wr[h*128 + c];
      float s = x * as_[h*128 + c], d = x * ad_[h*128 + c];
      for (int off = 32; off > 0; off >>= 1){ s += __shfl_down(s, off); d += __shfl_down(d, off); }
      if (lane == 0){ red4[w][0] = s; red4[w][1] = d; }
      __syncthreads();
      if (t == 0)  { Was[krow*3+h] = red4[0][0] + red4[1][0]; Wad[krow*3+h] = red4[0][1] + red4[1][1]; }
      if (t == 128){ Was[krow*3+h] = red4[2][0] + red4[3][0]; Wad[krow*3+h] = red4[2][1] + red4[3][1]; }
      __syncthreads();
    }
    return;
  }
  b -= 2048;
  if (b < 1819){                                    // ---- degree histogram
    int idx = b * 256 + t;
    if (idx >= EV + EH + 2*EC) return;
    const int* dp; int* cnt; int e;
    if      (idx < EV)       { dp=vdst;  cnt=cntV;  e=idx; }
    else if (idx < EV+EH)    { dp=hdst;  cnt=cntH;  e=idx-EV; }
    else if (idx < EV+EH+EC) { dp=c1dst; cnt=cntC1; e=idx-EV-EH; }
    else                     { dp=c2dst; cnt=cntC2; e=idx-EV-EH-EC; }
    atomicAdd(&cnt[dp[e]], 1);
    return;
  }
  b -= 1819;
  if (b < 256){                                     // ---- edge-weight sums
    int which = b >> 7, base = b & 127;
    const float* x = which ? hew : vew;
    float s = 0.f;
    for (int i = base*256 + t; i < EV; i += 128*256) s += x[i];
    for (int off = 32; off > 0; off >>= 1) s += __shfl_down(s, off);
    if (lane == 0) red4[w][0] = s;
    __syncthreads();
    if (t == 0) atomicAdd(&sums[which], red4[0][0]+red4[1][0]+red4[2][0]+red4[3][0]);
    return;
  }
  // ---- Kbuf dots (single block)
  for (int h = 0; h < 3; h++){
    float s = (t < 128) ? v_line[h*128+t] * v_atte[h*128+t] : 0.f;
    for (int off = 32; off > 0; off >>= 1) s += __shfl_down(s, off);
    if (lane == 0) red4[w][0] = s;
    __syncthreads();
    if (t == 0) Kbuf[h] = red4[0][0]+red4[1][0]+red4[2][0]+red4[3][0];
    __syncthreads();
    s = (t < 128) ? h_line[h*128+t] * h_atte[h*128+t] : 0.f;
    for (int off = 32; off > 0; off >>= 1) s += __shfl_down(s, off);
    if (lane == 0) red4[w][0] = s;
    __syncthreads();
    if (t == 0) Kbuf[3+h] = red4[0][0]+red4[1][0]+red4[2][0]+red4[3][0];
    __syncthreads();
  }
}

// ===========================================================================
// Dispatch 2 (k_prep): fused row pack+attention-dot | tiled transposes |
// coex^T dots | exclusive scans
// blocks: [0,13024) rowdot | [13024,13728) tp | [13728,13760) ndt | [13760,13764) scan
__global__ __launch_bounds__(256) void k_prep(
    const float* __restrict__ virus, const float* __restrict__ hostd, const float* __restrict__ coex,
    const float* __restrict__ vW, const float* __restrict__ linvW,
    const float* __restrict__ hW, const float* __restrict__ linhW,
    const float* __restrict__ vhW, const float* __restrict__ hvW,
    const float* __restrict__ WasV, const float* __restrict__ WadV,
    const float* __restrict__ WasH, const float* __restrict__ WadH,
    const float* __restrict__ WasC1, const float* __restrict__ WadC1,
    const float* __restrict__ WasC2, const float* __restrict__ WadC2,
    int* cntV, int* startsV, int* cntH, int* startsH,
    int* cntC1, int* startsC1, int* cntC2, int* startsC2,
    unsigned short* Avb, unsigned short* Ahb, unsigned short* Acb,
    unsigned short* Actb, unsigned short* BtV, unsigned short* BtH,
    unsigned short* BtVH, unsigned short* BtHV,
    float* asV, float* adV, float* asH, float* adH,
    float* asC1, float* adC1, float* asC2, float* adC2)
{
  __shared__ float scratch[64*65];                  // 16.6 KB, aliased per section
  int b = blockIdx.x, t = threadIdx.x;
  int lane = t & 63, w = t >> 6;

  if (b < 13024){                                   // ---- row pack + 6 dots
    const float* x; unsigned short* dstp; const float* Was; const float* Wad;
    float* ao; float* doo; int row;
    if (b < 6000)       { row=b;       x=virus; dstp=Avb; Was=WasV;  Wad=WadV;  ao=asV;  doo=adV; }
    else if (b < 12000) { row=b-6000;  x=hostd; dstp=Ahb; Was=WasH;  Wad=WadH;  ao=asH;  doo=adH; }
    else                { row=b-12000; x=coex;  dstp=Acb; Was=WasC1; Wad=WadC1; ao=asC1; doo=adC1; }
    float4 v = reinterpret_cast<const float4*>(x + (size_t)row * 1024)[t];
    ushort4 o; o.x = f2bf(v.x); o.y = f2bf(v.y); o.z = f2bf(v.z); o.w = f2bf(v.w);
    reinterpret_cast<ushort4*>(dstp + (size_t)row * 1024)[t] = o;
    // dots: k = 4t..4t+3; Was layout [k][3]
    const float4* Wp = reinterpret_cast<const float4*>(Was + t*12);
    float4 wa = Wp[0], wb = Wp[1], wcc = Wp[2];
    const float4* Dp = reinterpret_cast<const float4*>(Wad + t*12);
    float4 da = Dp[0], db = Dp[1], dcc = Dp[2];
    float r[6];
    r[0] = v.x*wa.x + v.y*wa.w + v.z*wb.z + v.w*wcc.y;
    r[1] = v.x*wa.y + v.y*wb.x + v.z*wb.w + v.w*wcc.z;
    r[2] = v.x*wa.z + v.y*wb.y + v.z*wcc.x + v.w*wcc.w;
    r[3] = v.x*da.x + v.y*da.w + v.z*db.z + v.w*dcc.y;
    r[4] = v.x*da.y + v.y*db.x + v.z*db.w + v.w*dcc.z;
    r[5] = v.x*da.z + v.y*db.y + v.z*dcc.x + v.w*dcc.w;
    for (int off = 32; off > 0; off >>= 1)
#pragma unroll
      for (int i = 0; i < 6; i++) r[i] += __shfl_down(r[i], off);
    float (*sh6)[6] = (float(*)[6])scratch;
    if (lane == 0)
#pragma unroll
      for (int i = 0; i < 6; i++) sh6[w][i] = r[i];
    __syncthreads();
    if (t < 6){
      float s = sh6[0][t] + sh6[1][t] + sh6[2][t] + sh6[3][t];
      if (t < 3) ao[row*3 + t] = s; else doo[row*3 + (t-3)] = s;
    }
    return;
  }
  b -= 13024;
  if (b < 704){                                     // ---- tiled transpose -> bf16
    float (*tp_lds)[65] = (float(*)[65])scratch;
    const float* src; unsigned short* dst; int Nc, roff, ntn, rel;
    if      (b < 256){ src=coex;  dst=Actb; Nc=1024; roff=0;   ntn=16; rel=b; }
    else if (b < 352){ src=vW;    dst=BtV;  Nc=384;  roff=0;   ntn=6;  rel=b-256; }
    else if (b < 384){ src=linvW; dst=BtV;  Nc=128;  roff=384; ntn=2;  rel=b-352; }
    else if (b < 480){ src=hW;    dst=BtH;  Nc=384;  roff=0;   ntn=6;  rel=b-384; }
    else if (b < 512){ src=linhW; dst=BtH;  Nc=128;  roff=384; ntn=2;  rel=b-480; }
    else if (b < 608){ src=vhW;   dst=BtVH; Nc=384;  roff=0;   ntn=6;  rel=b-512; }
    else             { src=hvW;   dst=BtHV; Nc=384;  roff=0;   ntn=6;  rel=b-608; }
    int tn = rel % ntn, tk = rel / ntn;
    int k0_ = tk * 64, n0 = tn * 64;
    int tx = t & 63, ty = t >> 6;
#pragma unroll
    for (int r = 0; r < 16; r++)
      tp_lds[ty + r*4][tx] = src[(size_t)(k0_ + ty + r*4) * Nc + n0 + tx];
    __syncthreads();
#pragma unroll
    for (int r = 0; r < 16; r++)
      dst[(size_t)(n0 + ty + r*4 + roff) * 1024 + k0_ + tx] = f2bf(tp_lds[tx][ty + r*4]);
    return;
  }
  b -= 704;
  if (b < 32){                                      // ---- coex^T dots
    float (*st)[32][6] = (float(*)[32][6])scratch;
    int c = t & 31, ks = t >> 5;
    int nn = b * 32 + c;
    float a[6] = {0,0,0,0,0,0};
    for (int k = ks*128; k < ks*128 + 128; k++){
      float xv = coex[(size_t)k*1024 + nn];
      a[0] += xv*WasC2[k*3+0]; a[1] += xv*WasC2[k*3+1]; a[2] += xv*WasC2[k*3+2];
      a[3] += xv*WadC2[k*3+0]; a[4] += xv*WadC2[k*3+1]; a[5] += xv*WadC2[k*3+2];
    }
#pragma unroll
    for (int j = 0; j < 6; j++) st[ks][c][j] = a[j];
    __syncthreads();
    if (t < 32){
      float r[6] = {0,0,0,0,0,0};
#pragma unroll
      for (int k = 0; k < 8; k++)
#pragma unroll
        for (int j = 0; j < 6; j++) r[j] += st[k][t][j];
      int n2 = b * 32 + t;
      asC2[n2*3] = r[0]; asC2[n2*3+1] = r[1]; asC2[n2*3+2] = r[2];
      adC2[n2*3] = r[3]; adC2[n2*3+1] = r[4]; adC2[n2*3+2] = r[5];
    }
    return;
  }
  b -= 32;                                          // ---- exclusive scans (4 blocks)
  int* ssc = (int*)scratch;
  int* cnt; int* st_; int N;
  switch (b){
    case 0:  cnt=cntV;  st_=startsV;  N=NV;   break;
    case 1:  cnt=cntH;  st_=startsH;  N=NH;   break;
    case 2:  cnt=cntC1; st_=startsC1; N=1024; break;
    default: cnt=cntC2; st_=startsC2; N=1024; break;
  }
  int chunk = (N + 255) >> 8;
  int lo = t * chunk, hi = lo + chunk;
  if (hi > N) hi = N;
  if (lo > N) lo = N;
  int s = 0;
  for (int i = lo; i < hi; i++) s += cnt[i];
  ssc[t] = s;
  __syncthreads();
  for (int off = 1; off < 256; off <<= 1){
    int v = (t >= off) ? ssc[t - off] : 0;
    __syncthreads();
    ssc[t] += v;
    __syncthreads();
  }
  int run = ssc[t] - s;
  for (int i = lo; i < hi; i++){ st_[i] = run; run += cnt[i]; }
  if (t == 255) st_[N] = ssc[255];
}

// ===========================================================================
// NT bf16 MFMA GEMM body — 128x64 block tile, 2x2 waves (each 64x32), K=1024.
// MODE 0: cols<384 -> bf16 xwb, cols>=384 -> f32 lin (ld 128). MODE 1: all bf16.
template<int MODE>
__device__ __forceinline__ void gemm_body(
    const unsigned short* __restrict__ A, const unsigned short* __restrict__ B,
    int M, int N, unsigned short* __restrict__ xwb, float* __restrict__ lin,
    int bx, int by)
{
  const int tid  = threadIdx.x;
  const int lane = tid & 63, w = tid >> 6;
  const int wr = w >> 1, wc = w & 1;
  const int R  = by * 128 + wr * 64;
  const int Cb = bx * 64 + wc * 32;
  const int r0 = lane & 15, kg = lane >> 4;

  const unsigned short* pa[4]; const unsigned short* pb[2];
  bool va[4], vb[2];
#pragma unroll
  for (int i = 0; i < 4; i++){
    int row = R + i * 16 + r0;
    va[i] = row < M;
    pa[i] = A + (size_t)(va[i] ? row : 0) * 1024 + kg * 8;
  }
#pragma unroll
  for (int j = 0; j < 2; j++){
    int col = Cb + j * 16 + r0;
    vb[j] = col < N;
    pb[j] = B + (size_t)(vb[j] ? col : 0) * 1024 + kg * 8;
  }
  const bf16x8 Z8 = {0,0,0,0,0,0,0,0};
  f32x4 acc[4][2];
#pragma unroll
  for (int i = 0; i < 4; i++)
#pragma unroll
    for (int j = 0; j < 2; j++) acc[i][j] = (f32x4){0.f,0.f,0.f,0.f};

  for (int kk = 0; kk < 1024; kk += 32){
    bf16x8 av[4], bv[2];
#pragma unroll
    for (int i = 0; i < 4; i++){
      bf16x8 ta = *reinterpret_cast<const bf16x8*>(pa[i] + kk);
      av[i] = va[i] ? ta : Z8;
    }
#pragma unroll
    for (int j = 0; j < 2; j++){
      bf16x8 tb = *reinterpret_cast<const bf16x8*>(pb[j] + kk);
      bv[j] = vb[j] ? tb : Z8;
    }
#pragma unroll
    for (int i = 0; i < 4; i++)
#pragma unroll
      for (int j = 0; j < 2; j++)
        acc[i][j] = __builtin_amdgcn_mfma_f32_16x16x32_bf16(av[i], bv[j], acc[i][j], 0, 0, 0);
  }

  const int cn = lane & 15, rq = (lane >> 4) * 4;
#pragma unroll
  for (int i = 0; i < 4; i++){
    int row0 = R + i * 16 + rq;
#pragma unroll
    for (int j = 0; j < 2; j++){
      int col = Cb + j * 16 + cn;
      if (col < N){
#pragma unroll
        for (int r = 0; r < 4; r++){
          int row = row0 + r;
          if (row < M){
            float v = acc[i][j][r];
            if (MODE == 0){
              if (col < 384) xwb[(size_t)row * 384 + col] = f2bf(v);
              else           lin[(size_t)row * 128 + col - 384] = v;
            } else {
              xwb[(size_t)row * 384 + col] = f2bf(v);
            }
          }
        }
      }
    }
  }
}

// Dispatch 3 (k_sg): 4 xw/lin GEMMs + CSR scatter
// blocks: [0,376) V | [376,752) H | [752,800) C1 | [800,848) C2 | [848,2667) scatter
__global__ __launch_bounds__(256) void k_sg(
    const unsigned short* Avb, const unsigned short* BtV, unsigned short* xwbV, float* linV,
    const unsigned short* Ahb, const unsigned short* BtH, unsigned short* xwbH, float* linH,
    const unsigned short* Acb,  const unsigned short* BtVH, unsigned short* xwbC1,
    const unsigned short* Actb, const unsigned short* BtHV, unsigned short* xwbC2,
    const int* vdst, const int* hdst, const int* c1dst, const int* c2dst,
    const int* stV, const int* stH, const int* st1, const int* st2,
    int* cuV, int* cuH, int* cu1, int* cu2,
    int* soV, int* soH, int* so1, int* so2)
{
  int b = blockIdx.x;
  if (b < 848){
    if (b < 376)       gemm_body<0>(Avb,  BtV,  NV,   512, xwbV,  linV, b & 7, b >> 3);
    else if (b < 752){ int g = b - 376; gemm_body<0>(Ahb,  BtH,  NH,   512, xwbH,  linH, g & 7, g >> 3); }
    else if (b < 800){ int g = b - 752; gemm_body<1>(Acb,  BtVH, 1024, 384, xwbC1, nullptr, g % 6, g / 6); }
    else             { int g = b - 800; gemm_body<1>(Actb, BtHV, 1024, 384, xwbC2, nullptr, g % 6, g / 6); }
    return;
  }
  int idx = (b - 848) * 256 + threadIdx.x;
  if (idx >= EV + EH + 2*EC) return;
  const int* dp; const int* st; int* cur; int* so; int e;
  if      (idx < EV)       { dp=vdst;  st=stV; cur=cuV; so=soV; e=idx; }
  else if (idx < EV+EH)    { dp=hdst;  st=stH; cur=cuH; so=soH; e=idx-EV; }
  else if (idx < EV+EH+EC) { dp=c1dst; st=st1; cur=cu1; so=so1; e=idx-EV-EH; }
  else                     { dp=c2dst; st=st2; cur=cu2; so=so2; e=idx-EV-EH-EC; }
  int d = dp[e];
  so[st[d] + atomicAdd(&cur[d], 1)] = e;
}

// ===========================================================================
// Dispatch 4 (k_gatbn): fused GAT (softmax + alpha + aggregate) x4 + BN stats
struct GatDesc {
  const unsigned short* xwb; const int* src; const int* sorted; const int* starts;
  const float* as_; const float* ad_; const float* Kc; const float* ew; const float* sumw;
  const float* bias; float* alpha; float* feat;
  int E; float invE;
};

__global__ __launch_bounds__(256) void k_gatbn(
    GatDesc dV, GatDesc dH, GatDesc d1, GatDesc d2,
    const float* __restrict__ linV, const float* __restrict__ linH, float* __restrict__ bnacc)
{
  int b = blockIdx.x, t = threadIdx.x;
  if (b >= 14048){                                  // ---- BN stats
    int bb = b - 14048;
    int which = bb >= 188;
    int r0 = (which ? bb - 188 : bb) * 32 + (t >> 7) * 16;
    int c = t & 127;
    const float* lin = which ? linH : linV;
    float s = 0.f, q = 0.f;
#pragma unroll
    for (int r = 0; r < 16; r++){
      int row = r0 + r;
      if (row < NV){
        float v = lin[(size_t)row * 128 + c];
        s += v; q += v * v;
      }
    }
    atomicAdd(&bnacc[which*256 + c],       s);
    atomicAdd(&bnacc[which*256 + 128 + c], q);
    return;
  }
  GatDesc d; int n;
  if (b < 6000)       { d = dV; n = b; }
  else if (b < 12000) { d = dH; n = b - 6000; }
  else if (b < 13024) { d = d1; n = b - 12000; }
  else                { d = d2; n = b - 13024; }

  const int lane = t & 63, w = t >> 6;
  const int c = t & 127, half = t >> 7;
  __shared__ float shx[GCAP][3];
  __shared__ int   shs[GCAP];
  __shared__ float redm[4][3], reds[4][3], shD[128][3];

  const int s0  = d.starts[n];
  const int deg = d.starts[n+1] - s0;
  const bool hasW = (d.ew != nullptr);
  float K0=0.f, K1=0.f, K2=0.f, wself=0.f;
  if (hasW){ K0=d.Kc[0]; K1=d.Kc[1]; K2=d.Kc[2]; wself = d.sumw[0] * d.invE; }
  const float ad0 = d.ad_[n*3], ad1 = d.ad_[n*3+1], ad2 = d.ad_[n*3+2];
  float sr0 = d.as_[n*3+0] + ad0 + wself*K0;  sr0 = sr0 >= 0.f ? sr0 : 0.2f*sr0;
  float sr1 = d.as_[n*3+1] + ad1 + wself*K1;  sr1 = sr1 >= 0.f ? sr1 : 0.2f*sr1;
  float sr2 = d.as_[n*3+2] + ad2 + wself*K2;  sr2 = sr2 >= 0.f ? sr2 : 0.2f*sr2;

  // pass A: raw scores + per-head max
  float mx0 = sr0, mx1 = sr1, mx2 = sr2;
  for (int i = t; i < deg; i += 256){
    int e = d.sorted[s0 + i];
    int s = d.src[e];
    float wv = hasW ? d.ew[e] : 0.f;
    float r0 = d.as_[s*3+0] + ad0 + wv*K0;  r0 = r0 >= 0.f ? r0 : 0.2f*r0;
    float r1 = d.as_[s*3+1] + ad1 + wv*K1;  r1 = r1 >= 0.f ? r1 : 0.2f*r1;
    float r2 = d.as_[s*3+2] + ad2 + wv*K2;  r2 = r2 >= 0.f ? r2 : 0.2f*r2;
    if (i < GCAP){ shs[i] = s; shx[i][0]=r0; shx[i][1]=r1; shx[i][2]=r2; }
    mx0 = fmaxf(mx0, r0); mx1 = fmaxf(mx1, r1); mx2 = fmaxf(mx2, r2);
  }
  for (int off = 32; off > 0; off >>= 1){
    mx0 = fmaxf(mx0, __shfl_down(mx0, off));
    mx1 = fmaxf(mx1, __shfl_down(mx1, off));
    mx2 = fmaxf(mx2, __shfl_down(mx2, off));
  }
  if (lane == 0){ redm[w][0]=mx0; redm[w][1]=mx1; redm[w][2]=mx2; }
  __syncthreads();
  const float M0 = fmaxf(fmaxf(redm[0][0],redm[1][0]), fmaxf(redm[2][0],redm[3][0]));
  const float M1 = fmaxf(fmaxf(redm[0][1],redm[1][1]), fmaxf(redm[2][1],redm[3][1]));
  const float M2 = fmaxf(fmaxf(redm[0][2],redm[1][2]), fmaxf(redm[2][2],redm[3][2]));

  // pass B: exp + sum
  float t0 = 0.f, t1 = 0.f, t2 = 0.f;
  for (int i = t; i < deg; i += 256){
    float r0, r1, r2;
    if (i < GCAP){ r0 = shx[i][0]; r1 = shx[i][1]; r2 = shx[i][2]; }
    else {
      int e = d.sorted[s0 + i]; int s = d.src[e];
      float wv = hasW ? d.ew[e] : 0.f;
      r0 = d.as_[s*3+0]+ad0+wv*K0; r0 = r0>=0.f?r0:0.2f*r0;
      r1 = d.as_[s*3+1]+ad1+wv*K1; r1 = r1>=0.f?r1:0.2f*r1;
      r2 = d.as_[s*3+2]+ad2+wv*K2; r2 = r2>=0.f?r2:0.2f*r2;
    }
    float e0 = expf(r0 - M0), e1 = expf(r1 - M1), e2 = expf(r2 - M2);
    if (i < GCAP){ shx[i][0]=e0; shx[i][1]=e1; shx[i][2]=e2; }
    t0 += e0; t1 += e1; t2 += e2;
  }
  for (int off = 32; off > 0; off >>= 1){
    t0 += __shfl_down(t0, off); t1 += __shfl_down(t1, off); t2 += __shfl_down(t2, off);
  }
  if (lane == 0){ reds[w][0]=t0; reds[w][1]=t1; reds[w][2]=t2; }
  __syncthreads();
  const float se0 = expf(sr0 - M0), se1 = expf(sr1 - M1), se2 = expf(sr2 - M2);
  const float i0 = 1.f / (reds[0][0]+reds[1][0]+reds[2][0]+reds[3][0] + se0 + 1e-16f);
  const float i1 = 1.f / (reds[0][1]+reds[1][1]+reds[2][1]+reds[3][1] + se1 + 1e-16f);
  const float i2 = 1.f / (reds[0][2]+reds[1][2]+reds[2][2]+reds[3][2] + se2 + 1e-16f);

  // pass C: alpha in original edge order
  for (int i = t; i < deg; i += 256){
    int e = d.sorted[s0 + i];
    float e0, e1, e2;
    if (i < GCAP){ e0 = shx[i][0]; e1 = shx[i][1]; e2 = shx[i][2]; }
    else {
      int s = d.src[e];
      float wv = hasW ? d.ew[e] : 0.f;
      float r0 = d.as_[s*3+0]+ad0+wv*K0; r0=r0>=0.f?r0:0.2f*r0;
      float r1 = d.as_[s*3+1]+ad1+wv*K1; r1=r1>=0.f?r1:0.2f*r1;
      float r2 = d.as_[s*3+2]+ad2+wv*K2; r2=r2>=0.f?r2:0.2f*r2;
      e0 = expf(r0-M0); e1 = expf(r1-M1); e2 = expf(r2-M2);
    }
    float* ap = d.alpha + (size_t)e * 3;
    ap[0] = e0 * i0; ap[1] = e1 * i1; ap[2] = e2 * i2;
  }
  if (t == 0){
    float* ap = d.alpha + (size_t)(d.E + n) * 3;
    ap[0] = se0 * i0; ap[1] = se1 * i1; ap[2] = se2 * i2;
  }

  // pass D: aggregation, edges split across the two thread-halves
  float f0, f1, f2;
  if (half == 0){
    const unsigned short* xn = d.xwb + (size_t)n * 384;
    f0 = bf2f(xn[c]) * se0; f1 = bf2f(xn[128+c]) * se1; f2 = bf2f(xn[256+c]) * se2;
  } else { f0 = f1 = f2 = 0.f; }
  for (int i = half; i < deg; i += 2){
    int s; float e0, e1, e2;
    if (i < GCAP){ s = shs[i]; e0 = shx[i][0]; e1 = shx[i][1]; e2 = shx[i][2]; }
    else {
      int e = d.sorted[s0 + i]; s = d.src[e];
      float wv = hasW ? d.ew[e] : 0.f;
      float r0 = d.as_[s*3+0]+ad0+wv*K0; r0=r0>=0.f?r0:0.2f*r0;
      float r1 = d.as_[s*3+1]+ad1+wv*K1; r1=r1>=0.f?r1:0.2f*r1;
      float r2 = d.as_[s*3+2]+ad2+wv*K2; r2=r2>=0.f?r2:0.2f*r2;
      e0 = expf(r0-M0); e1 = expf(r1-M1); e2 = expf(r2-M2);
    }
    const unsigned short* xs = d.xwb + (size_t)s * 384;
    f0 += bf2f(xs[c]) * e0; f1 += bf2f(xs[128+c]) * e1; f2 += bf2f(xs[256+c]) * e2;
  }
  if (half == 1){ shD[c][0] = f0; shD[c][1] = f1; shD[c][2] = f2; }
  __syncthreads();
  if (half == 0){
    f0 += shD[c][0]; f1 += shD[c][1]; f2 += shD[c][2];
    d.feat[(size_t)n*128 + c] = (f0*i0 + f1*i1 + f2*i2) * (1.f/3.f) + d.bias[c];
  }
}

// ===========================================================================
// Dispatch 5 (k_fin): BN-inline final GEMM, triple write.
__global__ __launch_bounds__(256) void k_fin(
    const float* __restrict__ linV, const float* __restrict__ linH,
    const float* __restrict__ bnacc, const float* __restrict__ g, const float* __restrict__ bb,
    float* __restrict__ o0, float* __restrict__ o1, float* __restrict__ o2)
{
  __shared__ float sA[128], hA[128], sB[128], hB[128];
  const int t = threadIdx.x;
  if (t < 128){
    float mu  = bnacc[t] * (1.f/NV);
    float var = bnacc[128+t] * (1.f/NV) - mu*mu;
    float rs  = rsqrtf(var + 1e-5f);
    sA[t] = rs * g[t]; hA[t] = bb[t] - mu * rs * g[t];
  } else {
    int j = t - 128;
    float mu  = bnacc[256+j] * (1.f/NV);
    float var = bnacc[384+j] * (1.f/NV) - mu*mu;
    float rs  = rsqrtf(var + 1e-5f);
    sB[j] = rs * g[j]; hB[j] = bb[j] - mu * rs * g[j];
  }
  __syncthreads();

  const int lane = t & 63, w = t >> 6;
  const int wr = w >> 1, wc = w & 1;
  const int R  = blockIdx.y * 128 + wr * 64;
  const int Cb = blockIdx.x * 128 + wc * 64;
  const int r0 = lane & 15, kg = lane >> 4;

  const float* pa[4]; const float* pb[4];
  bool va[4], vb[4];
#pragma unroll
  for (int i = 0; i < 4; i++){
    int row = R + i * 16 + r0;
    va[i] = row < NV;
    pa[i] = linV + (size_t)(va[i] ? row : 0) * 128 + kg * 8;
    int col = Cb + i * 16 + r0;
    vb[i] = col < NH;
    pb[i] = linH + (size_t)(vb[i] ? col : 0) * 128 + kg * 8;
  }
  const bf16x8 Z8 = {0,0,0,0,0,0,0,0};
  f32x4 acc[4][4];
#pragma unroll
  for (int i = 0; i < 4; i++)
#pragma unroll
    for (int j = 0; j < 4; j++) acc[i][j] = (f32x4){0.f,0.f,0.f,0.f};

  for (int kk = 0; kk < 128; kk += 32){
    const int kb = kk + kg * 8;
    bf16x8 av[4], bv[4];
#pragma unroll
    for (int i = 0; i < 4; i++){
      bf16x8 fa, fb;
#pragma unroll
      for (int e = 0; e < 8; e++){
        float v1 = fmaf(pa[i][kk + e], sA[kb + e], hA[kb + e]);
        v1 = v1 >= 0.f ? v1 : 0.01f * v1;
        fa[e] = (short)f2bf(v1);
        float v2 = fmaf(pb[i][kk + e], sB[kb + e], hB[kb + e]);
        v2 = v2 >= 0.f ? v2 : 0.01f * v2;
        fb[e] = (short)f2bf(v2);
      }
      av[i] = va[i] ? fa : Z8;
      bv[i] = vb[i] ? fb : Z8;
    }
#pragma unroll
    for (int i = 0; i < 4; i++)
#pragma unroll
      for (int j = 0; j < 4; j++)
        acc[i][j] = __builtin_amdgcn_mfma_f32_16x16x32_bf16(av[i], bv[j], acc[i][j], 0, 0, 0);
  }

  const int cn = lane & 15, rq = (lane >> 4) * 4;
#pragma unroll
  for (int i = 0; i < 4; i++){
    int row0 = R + i * 16 + rq;
#pragma unroll
    for (int j = 0; j < 4; j++){
      int col = Cb + j * 16 + cn;
      if (col < NH){
#pragma unroll
        for (int r = 0; r < 4; r++){
          int row = row0 + r;
          if (row < NV){
            size_t idx = (size_t)row * NH + col;
            float v = acc[i][j][r];
            o0[idx] = v; o1[idx] = v; o2[idx] = v + v;
          }
        }
      }
    }
  }
}

// ===========================================================================
extern "C" void kernel_launch(void* const* d_in, const int* in_sizes, int n_in,
                              void* d_out, int out_size, void* d_ws, size_t ws_size,
                              hipStream_t stream)
{
  (void)in_sizes; (void)n_in; (void)out_size; (void)ws_size;
  const float* virus  = (const float*)d_in[0];
  const float* hostd  = (const float*)d_in[1];
  const float* coex   = (const float*)d_in[2];
  const float* vew    = (const float*)d_in[3];
  const float* hew    = (const float*)d_in[4];
  const float* vW     = (const float*)d_in[5];
  const float* v_as   = (const float*)d_in[6];
  const float* v_ad   = (const float*)d_in[7];
  const float* v_bias = (const float*)d_in[8];
  const float* v_line = (const float*)d_in[9];
  const float* v_atte = (const float*)d_in[10];
  const float* hW     = (const float*)d_in[11];
  const float* h_as   = (const float*)d_in[12];
  const float* h_ad   = (const float*)d_in[13];
  const float* h_bias = (const float*)d_in[14];
  const float* h_line = (const float*)d_in[15];
  const float* h_atte = (const float*)d_in[16];
  const float* vhW    = (const float*)d_in[17];
  const float* vh_as  = (const float*)d_in[18];
  const float* vh_ad  = (const float*)d_in[19];
  const float* vh_bias= (const float*)d_in[20];
  const float* hvW    = (const float*)d_in[21];
  const float* hv_as  = (const float*)d_in[22];
  const float* hv_ad  = (const float*)d_in[23];
  const float* hv_bias= (const float*)d_in[24];
  const float* linvW  = (const float*)d_in[25];
  const float* linhW  = (const float*)d_in[27];   // biases 26/28 cancel in BN
  const float* bng    = (const float*)d_in[29];
  const float* bnb    = (const float*)d_in[30];
  const int* vei  = (const int*)d_in[31];
  const int* hei  = (const int*)d_in[32];
  const int* cei  = (const int*)d_in[33];
  const int* ceit = (const int*)d_in[34];

  float* out = (float*)d_out;
  float* o0 = out;
  float* o1 = out + 36000000ll;
  float* o2 = out + 72000000ll;
  float* alpha_v  = out + 108000000ll;
  float* alpha_h  = alpha_v  + 618000;
  float* alpha_vh = alpha_h  + 618000;
  float* alpha_hv = alpha_vh + 101376;
  float* feat_v   = alpha_hv + 101376;
  float* feat_h   = feat_v   + 768000;
  float* feat_vh  = feat_h   + 768000;
  float* feat_hv  = feat_vh  + 131072;

  // ---------------- workspace carve-up ----------------
  char* wp = (char*)d_ws;
  auto alloc = [&](size_t b) -> void* { void* p = wp; wp += (b + 255) & ~(size_t)255; return p; };
  unsigned short* Avb  = (unsigned short*)alloc((size_t)NV*1024*2);
  unsigned short* Ahb  = (unsigned short*)alloc((size_t)NH*1024*2);
  unsigned short* Acb  = (unsigned short*)alloc((size_t)1024*1024*2);
  unsigned short* Actb = (unsigned short*)alloc((size_t)1024*1024*2);
  unsigned short* BtV  = (unsigned short*)alloc((size_t)512*1024*2);
  unsigned short* BtH  = (unsigned short*)alloc((size_t)512*1024*2);
  unsigned short* BtVH = (unsigned short*)alloc((size_t)384*1024*2);
  unsigned short* BtHV = (unsigned short*)alloc((size_t)384*1024*2);
  unsigned short* xwbV = (unsigned short*)alloc((size_t)NV*384*2);
  unsigned short* xwbH = (unsigned short*)alloc((size_t)NH*384*2);
  unsigned short* xwbC1= (unsigned short*)alloc((size_t)1024*384*2);
  unsigned short* xwbC2= (unsigned short*)alloc((size_t)1024*384*2);
  float* linV = (float*)alloc((size_t)NV*128*4);
  float* linH = (float*)alloc((size_t)NH*128*4);
  float* asV  = (float*)alloc(NV*3*4);   float* adV  = (float*)alloc(NV*3*4);
  float* asH  = (float*)alloc(NH*3*4);   float* adH  = (float*)alloc(NH*3*4);
  float* asC1 = (float*)alloc(1024*3*4); float* adC1 = (float*)alloc(1024*3*4);
  float* asC2 = (float*)alloc(1024*3*4); float* adC2 = (float*)alloc(1024*3*4);
  float* WasV = (float*)alloc(1024*3*4); float* WadV = (float*)alloc(1024*3*4);
  float* WasH = (float*)alloc(1024*3*4); float* WadH = (float*)alloc(1024*3*4);
  float* WasC1= (float*)alloc(1024*3*4); float* WadC1= (float*)alloc(1024*3*4);
  float* WasC2= (float*)alloc(1024*3*4); float* WadC2= (float*)alloc(1024*3*4);
  int* startsV  = (int*)alloc((NV+1)*4);  int* sortedV  = (int*)alloc((size_t)EV*4);
  int* startsH  = (int*)alloc((NH+1)*4);  int* sortedH  = (int*)alloc((size_t)EH*4);
  int* startsC1 = (int*)alloc(1025*4);    int* sortedC1 = (int*)alloc((size_t)EC*4);
  int* startsC2 = (int*)alloc(1025*4);    int* sortedC2 = (int*)alloc((size_t)EC*4);
  float* Kbuf  = (float*)alloc(256);
  // zero-init region
  char* z0 = wp;
  int* cntV  = (int*)alloc(NV*4);   int* curV  = (int*)alloc(NV*4);
  int* cntH  = (int*)alloc(NH*4);   int* curH  = (int*)alloc(NH*4);
  int* cntC1 = (int*)alloc(1024*4); int* curC1 = (int*)alloc(1024*4);
  int* cntC2 = (int*)alloc(1024*4); int* curC2 = (int*)alloc(1024*4);
  float* sums  = (float*)alloc(256);
  float* bnacc = (float*)alloc(512*4);
  hipMemsetAsync(z0, 0, (size_t)(wp - z0), stream);

  const int* vsrc = vei,  *vdst = vei  + EV;
  const int* hsrc = hei,  *hdst = hei  + EH;
  const int* c1src= ceit, *c1dst= ceit + EC;   // vh GAT: transposed indices
  const int* c2src= cei,  *c2dst= cei  + EC;   // hv GAT: plain indices

  // 1: W·a scalars + histogram + ew sums + Kbuf
  k0<<<4124, 256, 0, stream>>>(vW, v_as, v_ad, hW, h_as, h_ad,
      vhW, vh_as, vh_ad, hvW, hv_as, hv_ad,
      vew, hew, v_line, v_atte, h_line, h_atte,
      vdst, hdst, c1dst, c2dst,
      WasV, WadV, WasH, WadH, WasC1, WadC1, WasC2, WadC2,
      sums, Kbuf, cntV, cntH, cntC1, cntC2);
  // 2: fused row pack+dot + transposes + coex^T dots + scans
  k_prep<<<13764, 256, 0, stream>>>(virus, hostd, coex,
      vW, linvW, hW, linhW, vhW, hvW,
      WasV, WadV, WasH, WadH, WasC1, WadC1, WasC2, WadC2,
      cntV, startsV, cntH, startsH, cntC1, startsC1, cntC2, startsC2,
      Avb, Ahb, Acb, Actb, BtV, BtH, BtVH, BtHV,
      asV, adV, asH, adH, asC1, adC1, asC2, adC2);
  // 3: xw GEMMs + CSR scatter
  k_sg<<<2667, 256, 0, stream>>>(Avb, BtV, xwbV, linV, Ahb, BtH, xwbH, linH,
      Acb, BtVH, xwbC1, Actb, BtHV, xwbC2,
      vdst, hdst, c1dst, c2dst,
      startsV, startsH, startsC1, startsC2,
      curV, curH, curC1, curC2,
      sortedV, sortedH, sortedC1, sortedC2);
  // 4: fused GAT x4 + BN stats
  {
    GatDesc dv = { xwbV,  vsrc,  sortedV,  startsV,  asV,  adV,  Kbuf,   vew, &sums[0], v_bias,
                   alpha_v,  feat_v,  EV, 1.f/EV };
    GatDesc dh = { xwbH,  hsrc,  sortedH,  startsH,  asH,  adH,  Kbuf+3, hew, &sums[1], h_bias,
                   alpha_h,  feat_h,  EH, 1.f/EH };
    GatDesc dc1= { xwbC1, c1src, sortedC1, startsC1, asC1, adC1, nullptr, nullptr, nullptr, vh_bias,
                   alpha_vh, feat_vh, EC, 0.f };
    GatDesc dc2= { xwbC2, c2src, sortedC2, startsC2, asC2, adC2, nullptr, nullptr, nullptr, hv_bias,
                   alpha_hv, feat_hv, EC, 0.f };
    k_gatbn<<<14424, 256, 0, stream>>>(dv, dh, dc1, dc2, linV, linH, bnacc);
  }
  // 5: BN-inline final GEMM, triple write
  k_fin<<<dim3(47,47), 256, 0, stream>>>(linV, linH, bnacc, bng, bnb, o0, o1, o2);
}

// Round 8
// 810.204 us; speedup vs baseline: 1.0335x; 1.0335x over previous
//
#include <hip/hip_runtime.h>

// ---------------------------------------------------------------------------
// VirusHostCoexistenceModel — 6-node graph:
//   memset -> k0 (Wa/hist/sums/kbuf) -> k_prep (pack+dot/tp/ndt/scan)
//   -> k_sg (LDS-dbuf gemm+scatter) -> k_gatbn -> k_fin
#define NV   6000
#define NH   6000
#define EV   200000
#define EH   200000
#define EC   32768
#define GCAP 256

typedef __attribute__((ext_vector_type(8))) short bf16x8;
typedef __attribute__((ext_vector_type(4))) float f32x4;

__device__ __forceinline__ unsigned short f2bf(float f){
  unsigned u = __float_as_uint(f);
  u += 0x7FFFu + ((u >> 16) & 1u);        // RNE bf16
  return (unsigned short)(u >> 16);
}
__device__ __forceinline__ float bf2f(unsigned short h){
  return __uint_as_float((unsigned)h << 16);
}

// ===========================================================================
// Dispatch 1 (k0): W·a scalars + edge histogram + edge-weight sums + Kbuf
__global__ __launch_bounds__(256) void k0(
    const float* __restrict__ vW, const float* __restrict__ v_as, const float* __restrict__ v_ad,
    const float* __restrict__ hW, const float* __restrict__ h_as, const float* __restrict__ h_ad,
    const float* __restrict__ vhW, const float* __restrict__ vh_as, const float* __restrict__ vh_ad,
    const float* __restrict__ hvW, const float* __restrict__ hv_as, const float* __restrict__ hv_ad,
    const float* __restrict__ vew, const float* __restrict__ hew,
    const float* __restrict__ v_line, const float* __restrict__ v_atte,
    const float* __restrict__ h_line, const float* __restrict__ h_atte,
    const int* __restrict__ vdst, const int* __restrict__ hdst,
    const int* __restrict__ c1dst, const int* __restrict__ c2dst,
    float* WasV, float* WadV, float* WasH, float* WadH,
    float* WasC1, float* WadC1, float* WasC2, float* WadC2,
    float* sums, float* Kbuf,
    int* cntV, int* cntH, int* cntC1, int* cntC2)
{
  __shared__ float red4[4][2];
  int b = blockIdx.x, t = threadIdx.x;
  int lane = t & 63, w = t >> 6;

  if (b < 2048){                                    // ---- Was/Wad (2 rows/block)
    int m = b >> 9;
    int krow = (b & 511) * 2 + (t >> 7);
    int c = t & 127;
    const float *W, *as_, *ad_; float *Was, *Wad;
    switch (m){
      case 0:  W=vW;  as_=v_as;  ad_=v_ad;  Was=WasV;  Wad=WadV;  break;
      case 1:  W=hW;  as_=h_as;  ad_=h_ad;  Was=WasH;  Wad=WadH;  break;
      case 2:  W=vhW; as_=vh_as; ad_=vh_ad; Was=WasC1; Wad=WadC1; break;
      default: W=hvW; as_=hv_as; ad_=hv_ad; Was=WasC2; Wad=WadC2; break;
    }
    const float* Wr = W + (size_t)krow * 384;
    for (int h = 0; h < 3; h++){
      float x = Wr[h*128 + c];
      float s = x * as_[h*128 + c], d = x * ad_[h*128 + c];
      for (int off = 32; off > 0; off >>= 1){ s += __shfl_down(s, off); d += __shfl_down(d, off); }
      if (lane == 0){ red4[w][0] = s; red4[w][1] = d; }
      __syncthreads();
      if (t == 0)  { Was[krow*3+h] = red4[0][0] + red4[1][0]; Wad[krow*3+h] = red4[0][1] + red4[1][1]; }
      if (t == 128){ Was[krow*3+h] = red4[2][0] + red4[3][0]; Wad[krow*3+h] = red4[2][1] + red4[3][1]; }
      __syncthreads();
    }
    return;
  }
  b -= 2048;
  if (b < 1819){                                    // ---- degree histogram
    int idx = b * 256 + t;
    if (idx >= EV + EH + 2*EC) return;
    const int* dp; int* cnt; int e;
    if      (idx < EV)       { dp=vdst;  cnt=cntV;  e=idx; }
    else if (idx < EV+EH)    { dp=hdst;  cnt=cntH;  e=idx-EV; }
    else if (idx < EV+EH+EC) { dp=c1dst; cnt=cntC1; e=idx-EV-EH; }
    else                     { dp=c2dst; cnt=cntC2; e=idx-EV-EH-EC; }
    atomicAdd(&cnt[dp[e]], 1);
    return;
  }
  b -= 1819;
  if (b < 256){                                     // ---- edge-weight sums
    int which = b >> 7, base = b & 127;
    const float* x = which ? hew : vew;
    float s = 0.f;
    for (int i = base*256 + t; i < EV; i += 128*256) s += x[i];
    for (int off = 32; off > 0; off >>= 1) s += __shfl_down(s, off);
    if (lane == 0) red4[w][0] = s;
    __syncthreads();
    if (t == 0) atomicAdd(&sums[which], red4[0][0]+red4[1][0]+red4[2][0]+red4[3][0]);
    return;
  }
  // ---- Kbuf dots (single block)
  for (int h = 0; h < 3; h++){
    float s = (t < 128) ? v_line[h*128+t] * v_atte[h*128+t] : 0.f;
    for (int off = 32; off > 0; off >>= 1) s += __shfl_down(s, off);
    if (lane == 0) red4[w][0] = s;
    __syncthreads();
    if (t == 0) Kbuf[h] = red4[0][0]+red4[1][0]+red4[2][0]+red4[3][0];
    __syncthreads();
    s = (t < 128) ? h_line[h*128+t] * h_atte[h*128+t] : 0.f;
    for (int off = 32; off > 0; off >>= 1) s += __shfl_down(s, off);
    if (lane == 0) red4[w][0] = s;
    __syncthreads();
    if (t == 0) Kbuf[3+h] = red4[0][0]+red4[1][0]+red4[2][0]+red4[3][0];
    __syncthreads();
  }
}

// ===========================================================================
// Dispatch 2 (k_prep): fused row pack+attention-dot | tiled transposes |
// coex^T dots | exclusive scans
__global__ __launch_bounds__(256) void k_prep(
    const float* __restrict__ virus, const float* __restrict__ hostd, const float* __restrict__ coex,
    const float* __restrict__ vW, const float* __restrict__ linvW,
    const float* __restrict__ hW, const float* __restrict__ linhW,
    const float* __restrict__ vhW, const float* __restrict__ hvW,
    const float* __restrict__ WasV, const float* __restrict__ WadV,
    const float* __restrict__ WasH, const float* __restrict__ WadH,
    const float* __restrict__ WasC1, const float* __restrict__ WadC1,
    const float* __restrict__ WasC2, const float* __restrict__ WadC2,
    int* cntV, int* startsV, int* cntH, int* startsH,
    int* cntC1, int* startsC1, int* cntC2, int* startsC2,
    unsigned short* Avb, unsigned short* Ahb, unsigned short* Acb,
    unsigned short* Actb, unsigned short* BtV, unsigned short* BtH,
    unsigned short* BtVH, unsigned short* BtHV,
    float* asV, float* adV, float* asH, float* adH,
    float* asC1, float* adC1, float* asC2, float* adC2)
{
  __shared__ float scratch[64*65];                  // 16.6 KB, aliased per section
  int b = blockIdx.x, t = threadIdx.x;
  int lane = t & 63, w = t >> 6;

  if (b < 13024){                                   // ---- row pack + 6 dots
    const float* x; unsigned short* dstp; const float* Was; const float* Wad;
    float* ao; float* doo; int row;
    if (b < 6000)       { row=b;       x=virus; dstp=Avb; Was=WasV;  Wad=WadV;  ao=asV;  doo=adV; }
    else if (b < 12000) { row=b-6000;  x=hostd; dstp=Ahb; Was=WasH;  Wad=WadH;  ao=asH;  doo=adH; }
    else                { row=b-12000; x=coex;  dstp=Acb; Was=WasC1; Wad=WadC1; ao=asC1; doo=adC1; }
    float4 v = reinterpret_cast<const float4*>(x + (size_t)row * 1024)[t];
    ushort4 o; o.x = f2bf(v.x); o.y = f2bf(v.y); o.z = f2bf(v.z); o.w = f2bf(v.w);
    reinterpret_cast<ushort4*>(dstp + (size_t)row * 1024)[t] = o;
    // dots: k = 4t..4t+3; Was layout [k][3]
    const float4* Wp = reinterpret_cast<const float4*>(Was + t*12);
    float4 wa = Wp[0], wb = Wp[1], wcc = Wp[2];
    const float4* Dp = reinterpret_cast<const float4*>(Wad + t*12);
    float4 da = Dp[0], db = Dp[1], dcc = Dp[2];
    float r[6];
    r[0] = v.x*wa.x + v.y*wa.w + v.z*wb.z + v.w*wcc.y;
    r[1] = v.x*wa.y + v.y*wb.x + v.z*wb.w + v.w*wcc.z;
    r[2] = v.x*wa.z + v.y*wb.y + v.z*wcc.x + v.w*wcc.w;
    r[3] = v.x*da.x + v.y*da.w + v.z*db.z + v.w*dcc.y;
    r[4] = v.x*da.y + v.y*db.x + v.z*db.w + v.w*dcc.z;
    r[5] = v.x*da.z + v.y*db.y + v.z*dcc.x + v.w*dcc.w;
    for (int off = 32; off > 0; off >>= 1)
#pragma unroll
      for (int i = 0; i < 6; i++) r[i] += __shfl_down(r[i], off);
    float (*sh6)[6] = (float(*)[6])scratch;
    if (lane == 0)
#pragma unroll
      for (int i = 0; i < 6; i++) sh6[w][i] = r[i];
    __syncthreads();
    if (t < 6){
      float s = sh6[0][t] + sh6[1][t] + sh6[2][t] + sh6[3][t];
      if (t < 3) ao[row*3 + t] = s; else doo[row*3 + (t-3)] = s;
    }
    return;
  }
  b -= 13024;
  if (b < 704){                                     // ---- tiled transpose -> bf16
    float (*tp_lds)[65] = (float(*)[65])scratch;
    const float* src; unsigned short* dst; int Nc, roff, ntn, rel;
    if      (b < 256){ src=coex;  dst=Actb; Nc=1024; roff=0;   ntn=16; rel=b; }
    else if (b < 352){ src=vW;    dst=BtV;  Nc=384;  roff=0;   ntn=6;  rel=b-256; }
    else if (b < 384){ src=linvW; dst=BtV;  Nc=128;  roff=384; ntn=2;  rel=b-352; }
    else if (b < 480){ src=hW;    dst=BtH;  Nc=384;  roff=0;   ntn=6;  rel=b-384; }
    else if (b < 512){ src=linhW; dst=BtH;  Nc=128;  roff=384; ntn=2;  rel=b-480; }
    else if (b < 608){ src=vhW;   dst=BtVH; Nc=384;  roff=0;   ntn=6;  rel=b-512; }
    else             { src=hvW;   dst=BtHV; Nc=384;  roff=0;   ntn=6;  rel=b-608; }
    int tn = rel % ntn, tk = rel / ntn;
    int k0_ = tk * 64, n0 = tn * 64;
    int tx = t & 63, ty = t >> 6;
#pragma unroll
    for (int r = 0; r < 16; r++)
      tp_lds[ty + r*4][tx] = src[(size_t)(k0_ + ty + r*4) * Nc + n0 + tx];
    __syncthreads();
#pragma unroll
    for (int r = 0; r < 16; r++)
      dst[(size_t)(n0 + ty + r*4 + roff) * 1024 + k0_ + tx] = f2bf(tp_lds[tx][ty + r*4]);
    return;
  }
  b -= 704;
  if (b < 32){                                      // ---- coex^T dots
    float (*st)[32][6] = (float(*)[32][6])scratch;
    int c = t & 31, ks = t >> 5;
    int nn = b * 32 + c;
    float a[6] = {0,0,0,0,0,0};
    for (int k = ks*128; k < ks*128 + 128; k++){
      float xv = coex[(size_t)k*1024 + nn];
      a[0] += xv*WasC2[k*3+0]; a[1] += xv*WasC2[k*3+1]; a[2] += xv*WasC2[k*3+2];
      a[3] += xv*WadC2[k*3+0]; a[4] += xv*WadC2[k*3+1]; a[5] += xv*WadC2[k*3+2];
    }
#pragma unroll
    for (int j = 0; j < 6; j++) st[ks][c][j] = a[j];
    __syncthreads();
    if (t < 32){
      float r[6] = {0,0,0,0,0,0};
#pragma unroll
      for (int k = 0; k < 8; k++)
#pragma unroll
        for (int j = 0; j < 6; j++) r[j] += st[k][t][j];
      int n2 = b * 32 + t;
      asC2[n2*3] = r[0]; asC2[n2*3+1] = r[1]; asC2[n2*3+2] = r[2];
      adC2[n2*3] = r[3]; adC2[n2*3+1] = r[4]; adC2[n2*3+2] = r[5];
    }
    return;
  }
  b -= 32;                                          // ---- exclusive scans (4 blocks)
  int* ssc = (int*)scratch;
  int* cnt; int* st_; int N;
  switch (b){
    case 0:  cnt=cntV;  st_=startsV;  N=NV;   break;
    case 1:  cnt=cntH;  st_=startsH;  N=NH;   break;
    case 2:  cnt=cntC1; st_=startsC1; N=1024; break;
    default: cnt=cntC2; st_=startsC2; N=1024; break;
  }
  int chunk = (N + 255) >> 8;
  int lo = t * chunk, hi = lo + chunk;
  if (hi > N) hi = N;
  if (lo > N) lo = N;
  int s = 0;
  for (int i = lo; i < hi; i++) s += cnt[i];
  ssc[t] = s;
  __syncthreads();
  for (int off = 1; off < 256; off <<= 1){
    int v = (t >= off) ? ssc[t - off] : 0;
    __syncthreads();
    ssc[t] += v;
    __syncthreads();
  }
  int run = ssc[t] - s;
  for (int i = lo; i < hi; i++){ st_[i] = run; run += cnt[i]; }
  if (t == 255) st_[N] = ssc[255];
}

// ===========================================================================
// NT bf16 MFMA GEMM body — 128x64 block tile, LDS double-buffered (reg-staged),
// BK=32, one barrier per K-step. 4 waves (2x2), each 64x32 via 4x2 16x16 frags.
// MODE 0: cols<384 -> bf16 xwb, cols>=384 -> f32 lin (ld 128). MODE 1: all bf16.
template<int MODE>
__device__ __forceinline__ void gemm_body(
    const unsigned short* __restrict__ A, const unsigned short* __restrict__ B,
    int M, int N, unsigned short* __restrict__ xwb, float* __restrict__ lin,
    int bx, int by, unsigned short* As, unsigned short* Bs)
{
  const int tid  = threadIdx.x;
  const int lane = tid & 63, wv = tid >> 6;
  const int wr = wv >> 1, wc = wv & 1;
  const int R  = by * 128;
  const int Cb = bx * 64;
  const int r0 = lane & 15, kg = lane >> 4;

  // staging coordinates: thread t covers 8 bf16 (16B) per round
  const int ar0 = tid >> 2;                // A rows 0..63 (round 0), +64 (round 1)
  const int ac  = (tid & 3) * 8;
  int gra0 = R + ar0;        if (gra0 >= M) gra0 = M - 1;   // clamp (masked at C-write)
  int gra1 = R + ar0 + 64;   if (gra1 >= M) gra1 = M - 1;
  const unsigned short* pa0 = A + (size_t)gra0 * 1024 + ac;
  const unsigned short* pa1 = A + (size_t)gra1 * 1024 + ac;
  const unsigned short* pb  = B + (size_t)(Cb + ar0) * 1024 + ac;   // N multiple of 64

  f32x4 acc[4][2];
#pragma unroll
  for (int i = 0; i < 4; i++)
#pragma unroll
    for (int j = 0; j < 2; j++) acc[i][j] = (f32x4){0.f,0.f,0.f,0.f};

  // prologue: stage K-tile 0 into buf 0
  bf16x8 nA0 = *reinterpret_cast<const bf16x8*>(pa0);
  bf16x8 nA1 = *reinterpret_cast<const bf16x8*>(pa1);
  bf16x8 nB  = *reinterpret_cast<const bf16x8*>(pb);
  *reinterpret_cast<bf16x8*>(&As[ar0*32 + ac])      = nA0;
  *reinterpret_cast<bf16x8*>(&As[(ar0+64)*32 + ac]) = nA1;
  *reinterpret_cast<bf16x8*>(&Bs[ar0*32 + ac])      = nB;
  __syncthreads();

  int cur = 0;
  for (int kt = 0; kt < 32; ++kt){
    const int kn = (kt + 1) * 32;
    if (kt < 31){                                    // issue next-tile loads early
      nA0 = *reinterpret_cast<const bf16x8*>(pa0 + kn);
      nA1 = *reinterpret_cast<const bf16x8*>(pa1 + kn);
      nB  = *reinterpret_cast<const bf16x8*>(pb  + kn);
    }
    unsigned short* Ab = As + cur * 4096;
    unsigned short* Bb = Bs + cur * 2048;
    bf16x8 af[4], bfr[2];
#pragma unroll
    for (int i = 0; i < 4; i++)
      af[i] = *reinterpret_cast<const bf16x8*>(&Ab[(wr*64 + i*16 + r0)*32 + kg*8]);
#pragma unroll
    for (int j = 0; j < 2; j++)
      bfr[j] = *reinterpret_cast<const bf16x8*>(&Bb[(wc*32 + j*16 + r0)*32 + kg*8]);
#pragma unroll
    for (int i = 0; i < 4; i++)
#pragma unroll
      for (int j = 0; j < 2; j++)
        acc[i][j] = __builtin_amdgcn_mfma_f32_16x16x32_bf16(af[i], bfr[j], acc[i][j], 0, 0, 0);
    if (kt < 31){                                    // write next tile to other buf
      int nxt = cur ^ 1;
      unsigned short* An = As + nxt * 4096;
      unsigned short* Bn = Bs + nxt * 2048;
      *reinterpret_cast<bf16x8*>(&An[ar0*32 + ac])      = nA0;
      *reinterpret_cast<bf16x8*>(&An[(ar0+64)*32 + ac]) = nA1;
      *reinterpret_cast<bf16x8*>(&Bn[ar0*32 + ac])      = nB;
      __syncthreads();
      cur = nxt;
    }
  }

  const int cn = lane & 15, rq = (lane >> 4) * 4;
#pragma unroll
  for (int i = 0; i < 4; i++){
    int row0 = R + wr*64 + i * 16 + rq;
#pragma unroll
    for (int j = 0; j < 2; j++){
      int col = Cb + wc*32 + j * 16 + cn;
      if (col < N){
#pragma unroll
        for (int r = 0; r < 4; r++){
          int row = row0 + r;
          if (row < M){
            float v = acc[i][j][r];
            if (MODE == 0){
              if (col < 384) xwb[(size_t)row * 384 + col] = f2bf(v);
              else           lin[(size_t)row * 128 + col - 384] = v;
            } else {
              xwb[(size_t)row * 384 + col] = f2bf(v);
            }
          }
        }
      }
    }
  }
}

// Dispatch 3 (k_sg): 4 xw/lin GEMMs + CSR scatter
// blocks: [0,376) V | [376,752) H | [752,800) C1 | [800,848) C2 | [848,2667) scatter
__global__ __launch_bounds__(256) void k_sg(
    const unsigned short* Avb, const unsigned short* BtV, unsigned short* xwbV, float* linV,
    const unsigned short* Ahb, const unsigned short* BtH, unsigned short* xwbH, float* linH,
    const unsigned short* Acb,  const unsigned short* BtVH, unsigned short* xwbC1,
    const unsigned short* Actb, const unsigned short* BtHV, unsigned short* xwbC2,
    const int* vdst, const int* hdst, const int* c1dst, const int* c2dst,
    const int* stV, const int* stH, const int* st1, const int* st2,
    int* cuV, int* cuH, int* cu1, int* cu2,
    int* soV, int* soH, int* so1, int* so2)
{
  __shared__ unsigned short As[2*4096];   // 16 KB
  __shared__ unsigned short Bs[2*2048];   //  8 KB
  int b = blockIdx.x;
  if (b < 848){
    if (b < 376)       gemm_body<0>(Avb,  BtV,  NV,   512, xwbV,  linV, b & 7, b >> 3, As, Bs);
    else if (b < 752){ int g = b - 376; gemm_body<0>(Ahb,  BtH,  NH,   512, xwbH,  linH, g & 7, g >> 3, As, Bs); }
    else if (b < 800){ int g = b - 752; gemm_body<1>(Acb,  BtVH, 1024, 384, xwbC1, nullptr, g % 6, g / 6, As, Bs); }
    else             { int g = b - 800; gemm_body<1>(Actb, BtHV, 1024, 384, xwbC2, nullptr, g % 6, g / 6, As, Bs); }
    return;
  }
  int idx = (b - 848) * 256 + threadIdx.x;
  if (idx >= EV + EH + 2*EC) return;
  const int* dp; const int* st; int* cur; int* so; int e;
  if      (idx < EV)       { dp=vdst;  st=stV; cur=cuV; so=soV; e=idx; }
  else if (idx < EV+EH)    { dp=hdst;  st=stH; cur=cuH; so=soH; e=idx-EV; }
  else if (idx < EV+EH+EC) { dp=c1dst; st=st1; cur=cu1; so=so1; e=idx-EV-EH; }
  else                     { dp=c2dst; st=st2; cur=cu2; so=so2; e=idx-EV-EH-EC; }
  int d = dp[e];
  so[st[d] + atomicAdd(&cur[d], 1)] = e;
}

// ===========================================================================
// Dispatch 4 (k_gatbn): fused GAT (softmax + alpha + aggregate) x4 + BN stats
struct GatDesc {
  const unsigned short* xwb; const int* src; const int* sorted; const int* starts;
  const float* as_; const float* ad_; const float* Kc; const float* ew; const float* sumw;
  const float* bias; float* alpha; float* feat;
  int E; float invE;
};

__global__ __launch_bounds__(256) void k_gatbn(
    GatDesc dV, GatDesc dH, GatDesc d1, GatDesc d2,
    const float* __restrict__ linV, const float* __restrict__ linH, float* __restrict__ bnacc)
{
  int b = blockIdx.x, t = threadIdx.x;
  if (b >= 14048){                                  // ---- BN stats
    int bb = b - 14048;
    int which = bb >= 188;
    int r0 = (which ? bb - 188 : bb) * 32 + (t >> 7) * 16;
    int c = t & 127;
    const float* lin = which ? linH : linV;
    float s = 0.f, q = 0.f;
#pragma unroll
    for (int r = 0; r < 16; r++){
      int row = r0 + r;
      if (row < NV){
        float v = lin[(size_t)row * 128 + c];
        s += v; q += v * v;
      }
    }
    atomicAdd(&bnacc[which*256 + c],       s);
    atomicAdd(&bnacc[which*256 + 128 + c], q);
    return;
  }
  GatDesc d; int n;
  if (b < 6000)       { d = dV; n = b; }
  else if (b < 12000) { d = dH; n = b - 6000; }
  else if (b < 13024) { d = d1; n = b - 12000; }
  else                { d = d2; n = b - 13024; }

  const int lane = t & 63, w = t >> 6;
  const int c = t & 127, half = t >> 7;
  __shared__ float shx[GCAP][3];
  __shared__ int   shs[GCAP];
  __shared__ float redm[4][3], reds[4][3], shD[128][3];

  const int s0  = d.starts[n];
  const int deg = d.starts[n+1] - s0;
  const bool hasW = (d.ew != nullptr);
  float K0=0.f, K1=0.f, K2=0.f, wself=0.f;
  if (hasW){ K0=d.Kc[0]; K1=d.Kc[1]; K2=d.Kc[2]; wself = d.sumw[0] * d.invE; }
  const float ad0 = d.ad_[n*3], ad1 = d.ad_[n*3+1], ad2 = d.ad_[n*3+2];
  float sr0 = d.as_[n*3+0] + ad0 + wself*K0;  sr0 = sr0 >= 0.f ? sr0 : 0.2f*sr0;
  float sr1 = d.as_[n*3+1] + ad1 + wself*K1;  sr1 = sr1 >= 0.f ? sr1 : 0.2f*sr1;
  float sr2 = d.as_[n*3+2] + ad2 + wself*K2;  sr2 = sr2 >= 0.f ? sr2 : 0.2f*sr2;

  // pass A: raw scores + per-head max
  float mx0 = sr0, mx1 = sr1, mx2 = sr2;
  for (int i = t; i < deg; i += 256){
    int e = d.sorted[s0 + i];
    int s = d.src[e];
    float wv = hasW ? d.ew[e] : 0.f;
    float r0 = d.as_[s*3+0] + ad0 + wv*K0;  r0 = r0 >= 0.f ? r0 : 0.2f*r0;
    float r1 = d.as_[s*3+1] + ad1 + wv*K1;  r1 = r1 >= 0.f ? r1 : 0.2f*r1;
    float r2 = d.as_[s*3+2] + ad2 + wv*K2;  r2 = r2 >= 0.f ? r2 : 0.2f*r2;
    if (i < GCAP){ shs[i] = s; shx[i][0]=r0; shx[i][1]=r1; shx[i][2]=r2; }
    mx0 = fmaxf(mx0, r0); mx1 = fmaxf(mx1, r1); mx2 = fmaxf(mx2, r2);
  }
  for (int off = 32; off > 0; off >>= 1){
    mx0 = fmaxf(mx0, __shfl_down(mx0, off));
    mx1 = fmaxf(mx1, __shfl_down(mx1, off));
    mx2 = fmaxf(mx2, __shfl_down(mx2, off));
  }
  if (lane == 0){ redm[w][0]=mx0; redm[w][1]=mx1; redm[w][2]=mx2; }
  __syncthreads();
  const float M0 = fmaxf(fmaxf(redm[0][0],redm[1][0]), fmaxf(redm[2][0],redm[3][0]));
  const float M1 = fmaxf(fmaxf(redm[0][1],redm[1][1]), fmaxf(redm[2][1],redm[3][1]));
  const float M2 = fmaxf(fmaxf(redm[0][2],redm[1][2]), fmaxf(redm[2][2],redm[3][2]));

  // pass B: exp + sum
  float t0 = 0.f, t1 = 0.f, t2 = 0.f;
  for (int i = t; i < deg; i += 256){
    float r0, r1, r2;
    if (i < GCAP){ r0 = shx[i][0]; r1 = shx[i][1]; r2 = shx[i][2]; }
    else {
      int e = d.sorted[s0 + i]; int s = d.src[e];
      float wv = hasW ? d.ew[e] : 0.f;
      r0 = d.as_[s*3+0]+ad0+wv*K0; r0 = r0>=0.f?r0:0.2f*r0;
      r1 = d.as_[s*3+1]+ad1+wv*K1; r1 = r1>=0.f?r1:0.2f*r1;
      r2 = d.as_[s*3+2]+ad2+wv*K2; r2 = r2>=0.f?r2:0.2f*r2;
    }
    float e0 = expf(r0 - M0), e1 = expf(r1 - M1), e2 = expf(r2 - M2);
    if (i < GCAP){ shx[i][0]=e0; shx[i][1]=e1; shx[i][2]=e2; }
    t0 += e0; t1 += e1; t2 += e2;
  }
  for (int off = 32; off > 0; off >>= 1){
    t0 += __shfl_down(t0, off); t1 += __shfl_down(t1, off); t2 += __shfl_down(t2, off);
  }
  if (lane == 0){ reds[w][0]=t0; reds[w][1]=t1; reds[w][2]=t2; }
  __syncthreads();
  const float se0 = expf(sr0 - M0), se1 = expf(sr1 - M1), se2 = expf(sr2 - M2);
  const float i0 = 1.f / (reds[0][0]+reds[1][0]+reds[2][0]+reds[3][0] + se0 + 1e-16f);
  const float i1 = 1.f / (reds[0][1]+reds[1][1]+reds[2][1]+reds[3][1] + se1 + 1e-16f);
  const float i2 = 1.f / (reds[0][2]+reds[1][2]+reds[2][2]+reds[3][2] + se2 + 1e-16f);

  // pass C: alpha in original edge order
  for (int i = t; i < deg; i += 256){
    int e = d.sorted[s0 + i];
    float e0, e1, e2;
    if (i < GCAP){ e0 = shx[i][0]; e1 = shx[i][1]; e2 = shx[i][2]; }
    else {
      int s = d.src[e];
      float wv = hasW ? d.ew[e] : 0.f;
      float r0 = d.as_[s*3+0]+ad0+wv*K0; r0=r0>=0.f?r0:0.2f*r0;
      float r1 = d.as_[s*3+1]+ad1+wv*K1; r1=r1>=0.f?r1:0.2f*r1;
      float r2 = d.as_[s*3+2]+ad2+wv*K2; r2=r2>=0.f?r2:0.2f*r2;
      e0 = expf(r0-M0); e1 = expf(r1-M1); e2 = expf(r2-M2);
    }
    float* ap = d.alpha + (size_t)e * 3;
    ap[0] = e0 * i0; ap[1] = e1 * i1; ap[2] = e2 * i2;
  }
  if (t == 0){
    float* ap = d.alpha + (size_t)(d.E + n) * 3;
    ap[0] = se0 * i0; ap[1] = se1 * i1; ap[2] = se2 * i2;
  }

  // pass D: aggregation, edges split across the two thread-halves
  float f0, f1, f2;
  if (half == 0){
    const unsigned short* xn = d.xwb + (size_t)n * 384;
    f0 = bf2f(xn[c]) * se0; f1 = bf2f(xn[128+c]) * se1; f2 = bf2f(xn[256+c]) * se2;
  } else { f0 = f1 = f2 = 0.f; }
  for (int i = half; i < deg; i += 2){
    int s; float e0, e1, e2;
    if (i < GCAP){ s = shs[i]; e0 = shx[i][0]; e1 = shx[i][1]; e2 = shx[i][2]; }
    else {
      int e = d.sorted[s0 + i]; s = d.src[e];
      float wv = hasW ? d.ew[e] : 0.f;
      float r0 = d.as_[s*3+0]+ad0+wv*K0; r0=r0>=0.f?r0:0.2f*r0;
      float r1 = d.as_[s*3+1]+ad1+wv*K1; r1=r1>=0.f?r1:0.2f*r1;
      float r2 = d.as_[s*3+2]+ad2+wv*K2; r2=r2>=0.f?r2:0.2f*r2;
      e0 = expf(r0-M0); e1 = expf(r1-M1); e2 = expf(r2-M2);
    }
    const unsigned short* xs = d.xwb + (size_t)s * 384;
    f0 += bf2f(xs[c]) * e0; f1 += bf2f(xs[128+c]) * e1; f2 += bf2f(xs[256+c]) * e2;
  }
  if (half == 1){ shD[c][0] = f0; shD[c][1] = f1; shD[c][2] = f2; }
  __syncthreads();
  if (half == 0){
    f0 += shD[c][0]; f1 += shD[c][1]; f2 += shD[c][2];
    d.feat[(size_t)n*128 + c] = (f0*i0 + f1*i1 + f2*i2) * (1.f/3.f) + d.bias[c];
  }
}

// ===========================================================================
// Dispatch 5 (k_fin): BN-inline final GEMM, triple write.
__global__ __launch_bounds__(256) void k_fin(
    const float* __restrict__ linV, const float* __restrict__ linH,
    const float* __restrict__ bnacc, const float* __restrict__ g, const float* __restrict__ bb,
    float* __restrict__ o0, float* __restrict__ o1, float* __restrict__ o2)
{
  __shared__ float sA[128], hA[128], sB[128], hB[128];
  const int t = threadIdx.x;
  if (t < 128){
    float mu  = bnacc[t] * (1.f/NV);
    float var = bnacc[128+t] * (1.f/NV) - mu*mu;
    float rs  = rsqrtf(var + 1e-5f);
    sA[t] = rs * g[t]; hA[t] = bb[t] - mu * rs * g[t];
  } else {
    int j = t - 128;
    float mu  = bnacc[256+j] * (1.f/NV);
    float var = bnacc[384+j] * (1.f/NV) - mu*mu;
    float rs  = rsqrtf(var + 1e-5f);
    sB[j] = rs * g[j]; hB[j] = bb[j] - mu * rs * g[j];
  }
  __syncthreads();

  const int lane = t & 63, w = t >> 6;
  const int wr = w >> 1, wc = w & 1;
  const int R  = blockIdx.y * 128 + wr * 64;
  const int Cb = blockIdx.x * 128 + wc * 64;
  const int r0 = lane & 15, kg = lane >> 4;

  const float* pa[4]; const float* pb[4];
  bool va[4], vb[4];
#pragma unroll
  for (int i = 0; i < 4; i++){
    int row = R + i * 16 + r0;
    va[i] = row < NV;
    pa[i] = linV + (size_t)(va[i] ? row : 0) * 128 + kg * 8;
    int col = Cb + i * 16 + r0;
    vb[i] = col < NH;
    pb[i] = linH + (size_t)(vb[i] ? col : 0) * 128 + kg * 8;
  }
  const bf16x8 Z8 = {0,0,0,0,0,0,0,0};
  f32x4 acc[4][4];
#pragma unroll
  for (int i = 0; i < 4; i++)
#pragma unroll
    for (int j = 0; j < 4; j++) acc[i][j] = (f32x4){0.f,0.f,0.f,0.f};

  for (int kk = 0; kk < 128; kk += 32){
    const int kb = kk + kg * 8;
    bf16x8 av[4], bv[4];
#pragma unroll
    for (int i = 0; i < 4; i++){
      bf16x8 fa, fb;
#pragma unroll
      for (int e = 0; e < 8; e++){
        float v1 = fmaf(pa[i][kk + e], sA[kb + e], hA[kb + e]);
        v1 = v1 >= 0.f ? v1 : 0.01f * v1;
        fa[e] = (short)f2bf(v1);
        float v2 = fmaf(pb[i][kk + e], sB[kb + e], hB[kb + e]);
        v2 = v2 >= 0.f ? v2 : 0.01f * v2;
        fb[e] = (short)f2bf(v2);
      }
      av[i] = va[i] ? fa : Z8;
      bv[i] = vb[i] ? fb : Z8;
    }
#pragma unroll
    for (int i = 0; i < 4; i++)
#pragma unroll
      for (int j = 0; j < 4; j++)
        acc[i][j] = __builtin_amdgcn_mfma_f32_16x16x32_bf16(av[i], bv[j], acc[i][j], 0, 0, 0);
  }

  const int cn = lane & 15, rq = (lane >> 4) * 4;
#pragma unroll
  for (int i = 0; i < 4; i++){
    int row0 = R + i * 16 + rq;
#pragma unroll
    for (int j = 0; j < 4; j++){
      int col = Cb + j * 16 + cn;
      if (col < NH){
#pragma unroll
        for (int r = 0; r < 4; r++){
          int row = row0 + r;
          if (row < NV){
            size_t idx = (size_t)row * NH + col;
            float v = acc[i][j][r];
            o0[idx] = v; o1[idx] = v; o2[idx] = v + v;
          }
        }
      }
    }
  }
}

// ===========================================================================
extern "C" void kernel_launch(void* const* d_in, const int* in_sizes, int n_in,
                              void* d_out, int out_size, void* d_ws, size_t ws_size,
                              hipStream_t stream)
{
  (void)in_sizes; (void)n_in; (void)out_size; (void)ws_size;
  const float* virus  = (const float*)d_in[0];
  const float* hostd  = (const float*)d_in[1];
  const float* coex   = (const float*)d_in[2];
  const float* vew    = (const float*)d_in[3];
  const float* hew    = (const float*)d_in[4];
  const float* vW     = (const float*)d_in[5];
  const float* v_as   = (const float*)d_in[6];
  const float* v_ad   = (const float*)d_in[7];
  const float* v_bias = (const float*)d_in[8];
  const float* v_line = (const float*)d_in[9];
  const float* v_atte = (const float*)d_in[10];
  const float* hW     = (const float*)d_in[11];
  const float* h_as   = (const float*)d_in[12];
  const float* h_ad   = (const float*)d_in[13];
  const float* h_bias = (const float*)d_in[14];
  const float* h_line = (const float*)d_in[15];
  const float* h_atte = (const float*)d_in[16];
  const float* vhW    = (const float*)d_in[17];
  const float* vh_as  = (const float*)d_in[18];
  const float* vh_ad  = (const float*)d_in[19];
  const float* vh_bias= (const float*)d_in[20];
  const float* hvW    = (const float*)d_in[21];
  const float* hv_as  = (const float*)d_in[22];
  const float* hv_ad  = (const float*)d_in[23];
  const float* hv_bias= (const float*)d_in[24];
  const float* linvW  = (const float*)d_in[25];
  const float* linhW  = (const float*)d_in[27];   // biases 26/28 cancel in BN
  const float* bng    = (const float*)d_in[29];
  const float* bnb    = (const float*)d_in[30];
  const int* vei  = (const int*)d_in[31];
  const int* hei  = (const int*)d_in[32];
  const int* cei  = (const int*)d_in[33];
  const int* ceit = (const int*)d_in[34];

  float* out = (float*)d_out;
  float* o0 = out;
  float* o1 = out + 36000000ll;
  float* o2 = out + 72000000ll;
  float* alpha_v  = out + 108000000ll;
  float* alpha_h  = alpha_v  + 618000;
  float* alpha_vh = alpha_h  + 618000;
  float* alpha_hv = alpha_vh + 101376;
  float* feat_v   = alpha_hv + 101376;
  float* feat_h   = feat_v   + 768000;
  float* feat_vh  = feat_h   + 768000;
  float* feat_hv  = feat_vh  + 131072;

  // ---------------- workspace carve-up ----------------
  char* wp = (char*)d_ws;
  auto alloc = [&](size_t b) -> void* { void* p = wp; wp += (b + 255) & ~(size_t)255; return p; };
  unsigned short* Avb  = (unsigned short*)alloc((size_t)NV*1024*2);
  unsigned short* Ahb  = (unsigned short*)alloc((size_t)NH*1024*2);
  unsigned short* Acb  = (unsigned short*)alloc((size_t)1024*1024*2);
  unsigned short* Actb = (unsigned short*)alloc((size_t)1024*1024*2);
  unsigned short* BtV  = (unsigned short*)alloc((size_t)512*1024*2);
  unsigned short* BtH  = (unsigned short*)alloc((size_t)512*1024*2);
  unsigned short* BtVH = (unsigned short*)alloc((size_t)384*1024*2);
  unsigned short* BtHV = (unsigned short*)alloc((size_t)384*1024*2);
  unsigned short* xwbV = (unsigned short*)alloc((size_t)NV*384*2);
  unsigned short* xwbH = (unsigned short*)alloc((size_t)NH*384*2);
  unsigned short* xwbC1= (unsigned short*)alloc((size_t)1024*384*2);
  unsigned short* xwbC2= (unsigned short*)alloc((size_t)1024*384*2);
  float* linV = (float*)alloc((size_t)NV*128*4);
  float* linH = (float*)alloc((size_t)NH*128*4);
  float* asV  = (float*)alloc(NV*3*4);   float* adV  = (float*)alloc(NV*3*4);
  float* asH  = (float*)alloc(NH*3*4);   float* adH  = (float*)alloc(NH*3*4);
  float* asC1 = (float*)alloc(1024*3*4); float* adC1 = (float*)alloc(1024*3*4);
  float* asC2 = (float*)alloc(1024*3*4); float* adC2 = (float*)alloc(1024*3*4);
  float* WasV = (float*)alloc(1024*3*4); float* WadV = (float*)alloc(1024*3*4);
  float* WasH = (float*)alloc(1024*3*4); float* WadH = (float*)alloc(1024*3*4);
  float* WasC1= (float*)alloc(1024*3*4); float* WadC1= (float*)alloc(1024*3*4);
  float* WasC2= (float*)alloc(1024*3*4); float* WadC2= (float*)alloc(1024*3*4);
  int* startsV  = (int*)alloc((NV+1)*4);  int* sortedV  = (int*)alloc((size_t)EV*4);
  int* startsH  = (int*)alloc((NH+1)*4);  int* sortedH  = (int*)alloc((size_t)EH*4);
  int* startsC1 = (int*)alloc(1025*4);    int* sortedC1 = (int*)alloc((size_t)EC*4);
  int* startsC2 = (int*)alloc(1025*4);    int* sortedC2 = (int*)alloc((size_t)EC*4);
  float* Kbuf  = (float*)alloc(256);
  // zero-init region
  char* z0 = wp;
  int* cntV  = (int*)alloc(NV*4);   int* curV  = (int*)alloc(NV*4);
  int* cntH  = (int*)alloc(NH*4);   int* curH  = (int*)alloc(NH*4);
  int* cntC1 = (int*)alloc(1024*4); int* curC1 = (int*)alloc(1024*4);
  int* cntC2 = (int*)alloc(1024*4); int* curC2 = (int*)alloc(1024*4);
  float* sums  = (float*)alloc(256);
  float* bnacc = (float*)alloc(512*4);
  hipMemsetAsync(z0, 0, (size_t)(wp - z0), stream);

  const int* vsrc = vei,  *vdst = vei  + EV;
  const int* hsrc = hei,  *hdst = hei  + EH;
  const int* c1src= ceit, *c1dst= ceit + EC;   // vh GAT: transposed indices
  const int* c2src= cei,  *c2dst= cei  + EC;   // hv GAT: plain indices

  // 1: W·a scalars + histogram + ew sums + Kbuf
  k0<<<4124, 256, 0, stream>>>(vW, v_as, v_ad, hW, h_as, h_ad,
      vhW, vh_as, vh_ad, hvW, hv_as, hv_ad,
      vew, hew, v_line, v_atte, h_line, h_atte,
      vdst, hdst, c1dst, c2dst,
      WasV, WadV, WasH, WadH, WasC1, WadC1, WasC2, WadC2,
      sums, Kbuf, cntV, cntH, cntC1, cntC2);
  // 2: fused row pack+dot + transposes + coex^T dots + scans
  k_prep<<<13764, 256, 0, stream>>>(virus, hostd, coex,
      vW, linvW, hW, linhW, vhW, hvW,
      WasV, WadV, WasH, WadH, WasC1, WadC1, WasC2, WadC2,
      cntV, startsV, cntH, startsH, cntC1, startsC1, cntC2, startsC2,
      Avb, Ahb, Acb, Actb, BtV, BtH, BtVH, BtHV,
      asV, adV, asH, adH, asC1, adC1, asC2, adC2);
  // 3: xw GEMMs (LDS double-buffered) + CSR scatter
  k_sg<<<2667, 256, 0, stream>>>(Avb, BtV, xwbV, linV, Ahb, BtH, xwbH, linH,
      Acb, BtVH, xwbC1, Actb, BtHV, xwbC2,
      vdst, hdst, c1dst, c2dst,
      startsV, startsH, startsC1, startsC2,
      curV, curH, curC1, curC2,
      sortedV, sortedH, sortedC1, sortedC2);
  // 4: fused GAT x4 + BN stats
  {
    GatDesc dv = { xwbV,  vsrc,  sortedV,  startsV,  asV,  adV,  Kbuf,   vew, &sums[0], v_bias,
                   alpha_v,  feat_v,  EV, 1.f/EV };
    GatDesc dh = { xwbH,  hsrc,  sortedH,  startsH,  asH,  adH,  Kbuf+3, hew, &sums[1], h_bias,
                   alpha_h,  feat_h,  EH, 1.f/EH };
    GatDesc dc1= { xwbC1, c1src, sortedC1, startsC1, asC1, adC1, nullptr, nullptr, nullptr, vh_bias,
                   alpha_vh, feat_vh, EC, 0.f };
    GatDesc dc2= { xwbC2, c2src, sortedC2, startsC2, asC2, adC2, nullptr, nullptr, nullptr, hv_bias,
                   alpha_hv, feat_hv, EC, 0.f };
    k_gatbn<<<14424, 256, 0, stream>>>(dv, dh, dc1, dc2, linV, linH, bnacc);
  }
  // 5: BN-inline final GEMM, triple write
  k_fin<<<dim3(47,47), 256, 0, stream>>>(linV, linH, bnacc, bng, bnb, o0, o1, o2);
}